// Round 1
// baseline (1360.352 us; speedup 1.0000x reference)
//
#include <hip/hip_runtime.h>
#include <hip/hip_bf16.h>

// Problem constants
#define B_  8
#define D_  256
#define N_  2048
#define M_  2048
#define H_  4
#define DH_ 64
#define D2_ 512

// ---------------------------------------------------------------------------
// Generic 64x64 f32 tiled-GEMM body (BM=64, BN=64, BK=16, 256 threads,
// 4x4 micro-tile per thread). A is [rows x KDIM] row-major, C ld = N_.
// BEXPR is an expression in (gk, gn) producing B[gk][gn].
// ---------------------------------------------------------------------------
#define GEMM_BODY(KDIM, BEXPR)                                                  \
  __shared__ float As[16][68];                                                  \
  __shared__ float Bs[16][68];                                                  \
  const int t = threadIdx.x;                                                    \
  const int m0 = blockIdx.y * 64, n0 = blockIdx.x * 64;                         \
  const int tx = t & 15, ty = t >> 4;                                           \
  float acc[4][4] = {};                                                         \
  for (int k0 = 0; k0 < (KDIM); k0 += 16) {                                     \
    {                                                                           \
      int c = t & 15, r0 = t >> 4;                                              \
      _Pragma("unroll") for (int p = 0; p < 4; ++p) {                           \
        int mm = r0 + 16 * p;                                                   \
        As[c][mm] = A[(size_t)(m0 + mm) * (KDIM) + k0 + c];                     \
      }                                                                         \
    }                                                                           \
    {                                                                           \
      int nn = t & 63, r0 = t >> 6;                                             \
      _Pragma("unroll") for (int p = 0; p < 4; ++p) {                           \
        int kk = r0 + 4 * p;                                                    \
        int gk = k0 + kk;                                                       \
        int gn = n0 + nn;                                                       \
        Bs[kk][nn] = (BEXPR);                                                   \
      }                                                                         \
    }                                                                           \
    __syncthreads();                                                            \
    _Pragma("unroll") for (int kk = 0; kk < 16; ++kk) {                         \
      float4 av = *(const float4*)&As[kk][ty * 4];                              \
      float4 bv = *(const float4*)&Bs[kk][tx * 4];                              \
      acc[0][0] += av.x * bv.x; acc[0][1] += av.x * bv.y;                       \
      acc[0][2] += av.x * bv.z; acc[0][3] += av.x * bv.w;                       \
      acc[1][0] += av.y * bv.x; acc[1][1] += av.y * bv.y;                       \
      acc[1][2] += av.y * bv.z; acc[1][3] += av.y * bv.w;                       \
      acc[2][0] += av.z * bv.x; acc[2][1] += av.z * bv.y;                       \
      acc[2][2] += av.z * bv.z; acc[2][3] += av.z * bv.w;                       \
      acc[3][0] += av.w * bv.x; acc[3][1] += av.w * bv.y;                       \
      acc[3][2] += av.w * bv.z; acc[3][3] += av.w * bv.w;                       \
    }                                                                           \
    __syncthreads();                                                            \
  }                                                                             \
  _Pragma("unroll") for (int mi = 0; mi < 4; ++mi) {                            \
    int row = m0 + ty * 4 + mi;                                                 \
    float bb = bias[row];                                                       \
    float4 r;                                                                   \
    r.x = acc[mi][0] + bb; r.y = acc[mi][1] + bb;                               \
    r.z = acc[mi][2] + bb; r.w = acc[mi][3] + bb;                               \
    *(float4*)&Cdst[(size_t)row * N_ + n0 + tx * 4] = r;                        \
  }

// ---------------------------------------------------------------------------
// 1) QKV projection: per batch, {Q,K,V}[256 x 2048] = W[256x256] @ src + bias
//    Q/K/V stored [B][H*DH][N], row = h*64 + d (matches Wq flat row h*DH+k).
// grid: (32, 4, B*3)
// ---------------------------------------------------------------------------
__global__ __launch_bounds__(256) void qkv_gemm(
    const float* __restrict__ x, const float* __restrict__ source,
    const float* __restrict__ Wq, const float* __restrict__ bq,
    const float* __restrict__ Wk, const float* __restrict__ bk,
    const float* __restrict__ Wv, const float* __restrict__ bv,
    float* __restrict__ Qg, float* __restrict__ Kg, float* __restrict__ Vg) {
  const int z = blockIdx.z;
  const int b = z / 3, w = z % 3;
  const float* A;
  const float* bias;
  const float* Bsrc;
  float* Cdst;
  if (w == 0) {
    A = Wq; bias = bq;
    Bsrc = x + (size_t)b * D_ * N_;
    Cdst = Qg + (size_t)b * D_ * N_;
  } else if (w == 1) {
    A = Wk; bias = bk;
    Bsrc = source + (size_t)b * D_ * M_;
    Cdst = Kg + (size_t)b * D_ * M_;
  } else {
    A = Wv; bias = bv;
    Bsrc = source + (size_t)b * D_ * M_;
    Cdst = Vg + (size_t)b * D_ * M_;
  }
  GEMM_BODY(256, Bsrc[(size_t)gk * N_ + gn])
}

// ---------------------------------------------------------------------------
// 2) Flash attention (f32). One block = 64 queries of one (b,h).
//    K-tiles of 32 keys, online softmax. Writes msgC[b][c][n], c = d*H + h.
// grid: (N/64, H, B), 256 threads
// ---------------------------------------------------------------------------
__global__ __launch_bounds__(256) void attn_kernel(
    const float* __restrict__ Qg, const float* __restrict__ Kg,
    const float* __restrict__ Vg, float* __restrict__ msgC) {
  __shared__ float Qs[64][68];  // [q][d]
  __shared__ float Ks[32][68];  // [m][d]
  __shared__ float Vs[64][36];  // [d][m]
  __shared__ float Ps[64][36];  // [q][m]
  const int t = threadIdx.x;
  const int qt = blockIdx.x, h = blockIdx.y, b = blockIdx.z;
  const size_t base = ((size_t)(b * H_ + h)) * DH_ * (size_t)N_;
  const float* Qb = Qg + base;
  const float* Kb = Kg + base;
  const float* Vb = Vg + base;
  const int n00 = qt * 64;

  for (int idx = t; idx < 4096; idx += 256) {
    int d = idx >> 6, q = idx & 63;
    Qs[q][d] = Qb[(size_t)d * N_ + n00 + q];
  }
  const int q = t >> 2, j = t & 3;
  float O[16];
#pragma unroll
  for (int i = 0; i < 16; ++i) O[i] = 0.f;
  float s[8];
  float mq = -1e30f, lq = 0.f;
  __syncthreads();

  for (int m0 = 0; m0 < M_; m0 += 32) {
    for (int idx = t; idx < 2048; idx += 256) {
      int d = idx >> 5, m = idx & 31;
      Ks[m][d] = Kb[(size_t)d * M_ + m0 + m];
      Vs[d][m] = Vb[(size_t)d * M_ + m0 + m];
    }
    __syncthreads();
#pragma unroll
    for (int i = 0; i < 8; ++i) s[i] = 0.f;
#pragma unroll
    for (int d4 = 0; d4 < 16; ++d4) {
      float4 qv = *(const float4*)&Qs[q][d4 * 4];
#pragma unroll
      for (int i = 0; i < 8; ++i) {
        float4 kv = *(const float4*)&Ks[j + 4 * i][d4 * 4];
        s[i] += qv.x * kv.x + qv.y * kv.y + qv.z * kv.z + qv.w * kv.w;
      }
    }
    float tm = -1e30f;
#pragma unroll
    for (int i = 0; i < 8; ++i) {
      s[i] *= 0.125f;  // 1/sqrt(64)
      tm = fmaxf(tm, s[i]);
    }
    tm = fmaxf(tm, __shfl_xor(tm, 1));
    tm = fmaxf(tm, __shfl_xor(tm, 2));
    float Mn = fmaxf(mq, tm);
    float scl = __expf(mq - Mn);
    float ls = 0.f;
#pragma unroll
    for (int i = 0; i < 8; ++i) {
      s[i] = __expf(s[i] - Mn);
      ls += s[i];
    }
    ls += __shfl_xor(ls, 1);
    ls += __shfl_xor(ls, 2);
    lq = lq * scl + ls;
#pragma unroll
    for (int i = 0; i < 16; ++i) O[i] *= scl;
    mq = Mn;
#pragma unroll
    for (int i = 0; i < 8; ++i) Ps[q][j + 4 * i] = s[i];
    __syncthreads();
#pragma unroll
    for (int m4 = 0; m4 < 8; ++m4) {
      float4 pv = *(const float4*)&Ps[q][m4 * 4];
#pragma unroll
      for (int i = 0; i < 16; ++i) {
        float4 vv = *(const float4*)&Vs[j + 4 * i][m4 * 4];
        O[i] += pv.x * vv.x + pv.y * vv.y + pv.z * vv.z + pv.w * vv.w;
      }
    }
    __syncthreads();
  }
  float inv = 1.f / lq;
#pragma unroll
  for (int i = 0; i < 16; ++i) {
    int d = j + 4 * i;
    int c = d * H_ + h;  // dim-major reshape: c = k*H + h
    msgC[((size_t)b * D_ + c) * N_ + n00 + q] = O[i] * inv;
  }
}

// ---------------------------------------------------------------------------
// 3) merge: message = Wm @ msgC + bm, per batch.  grid: (32, 4, B)
// ---------------------------------------------------------------------------
__global__ __launch_bounds__(256) void merge_gemm(
    const float* __restrict__ msgC, const float* __restrict__ Wm,
    const float* __restrict__ bm, float* __restrict__ msg2) {
  const int b = blockIdx.z;
  const float* A = Wm;
  const float* bias = bm;
  const float* Bsrc = msgC + (size_t)b * D_ * N_;
  float* Cdst = msg2 + (size_t)b * D_ * N_;
  GEMM_BODY(256, Bsrc[(size_t)gk * N_ + gn])
}

// ---------------------------------------------------------------------------
// 4) W1: h1 = W1 @ concat(x, message) + b1.  grid: (32, 8, B)
// ---------------------------------------------------------------------------
__global__ __launch_bounds__(256) void w1_gemm(
    const float* __restrict__ x, const float* __restrict__ msg2,
    const float* __restrict__ W1, const float* __restrict__ b1,
    float* __restrict__ h1) {
  const int b = blockIdx.z;
  const float* A = W1;
  const float* bias = b1;
  const float* xb = x + (size_t)b * D_ * N_;
  const float* msgb = msg2 + (size_t)b * D_ * N_;
  float* Cdst = h1 + (size_t)b * D2_ * N_;
  GEMM_BODY(512, (gk < 256 ? xb[(size_t)gk * N_ + gn]
                           : msgb[(size_t)(gk - 256) * N_ + gn]))
}

// ---------------------------------------------------------------------------
// 5) InstanceNorm stats: mean/istd per (b,c) row of h1.  grid: (B*512)
// ---------------------------------------------------------------------------
__global__ __launch_bounds__(256) void stats_kernel(
    const float* __restrict__ h1, float* __restrict__ mean,
    float* __restrict__ istd) {
  const int row = blockIdx.x;
  const float* p = h1 + (size_t)row * N_;
  float s = 0.f, ss = 0.f;
  for (int i = threadIdx.x; i < N_; i += 256) {
    float v = p[i];
    s += v;
    ss += v * v;
  }
#pragma unroll
  for (int o = 1; o < 64; o <<= 1) {
    s += __shfl_xor(s, o);
    ss += __shfl_xor(ss, o);
  }
  __shared__ float red[2][4];
  const int w = threadIdx.x >> 6;
  if ((threadIdx.x & 63) == 0) {
    red[0][w] = s;
    red[1][w] = ss;
  }
  __syncthreads();
  if (threadIdx.x == 0) {
    float S = red[0][0] + red[0][1] + red[0][2] + red[0][3];
    float SS = red[1][0] + red[1][1] + red[1][2] + red[1][3];
    float mn = S * (1.f / N_);
    float var = SS * (1.f / N_) - mn * mn;
    mean[row] = mn;
    istd[row] = rsqrtf(var + 1e-5f);
  }
}

// ---------------------------------------------------------------------------
// 6) W2: out = W2 @ relu(instnorm(h1)) + b2 (norm+relu fused into B loader).
// grid: (32, 4, B)
// ---------------------------------------------------------------------------
__global__ __launch_bounds__(256) void w2_gemm(
    const float* __restrict__ h1, const float* __restrict__ mean,
    const float* __restrict__ istd, const float* __restrict__ W2,
    const float* __restrict__ b2, float* __restrict__ out) {
  const int b = blockIdx.z;
  const float* A = W2;
  const float* bias = b2;
  const float* Bsrc = h1 + (size_t)b * D2_ * N_;
  const float* meanp = mean + b * D2_;
  const float* istdp = istd + b * D2_;
  float* Cdst = out + (size_t)b * D_ * N_;
  GEMM_BODY(512,
            fmaxf((Bsrc[(size_t)gk * N_ + gn] - meanp[gk]) * istdp[gk], 0.f))
}

// ---------------------------------------------------------------------------
extern "C" void kernel_launch(void* const* d_in, const int* in_sizes, int n_in,
                              void* d_out, int out_size, void* d_ws,
                              size_t ws_size, hipStream_t stream) {
  const float* x = (const float*)d_in[0];
  const float* source = (const float*)d_in[1];
  const float* Wq = (const float*)d_in[2];
  const float* bq = (const float*)d_in[3];
  const float* Wk = (const float*)d_in[4];
  const float* bk = (const float*)d_in[5];
  const float* Wv = (const float*)d_in[6];
  const float* bv = (const float*)d_in[7];
  const float* Wm = (const float*)d_in[8];
  const float* bm = (const float*)d_in[9];
  const float* W1 = (const float*)d_in[10];
  const float* b1 = (const float*)d_in[11];
  const float* W2 = (const float*)d_in[12];
  const float* b2 = (const float*)d_in[13];
  float* out = (float*)d_out;

  float* ws = (float*)d_ws;
  const size_t SZ = (size_t)B_ * D_ * N_;  // 4,194,304
  float* Qg = ws;
  float* Kg = Qg + SZ;
  float* Vg = Kg + SZ;
  float* msgC = Vg + SZ;
  float* msg2 = msgC + SZ;
  float* h1 = msg2 + SZ;          // 2*SZ elements
  float* mean = h1 + 2 * SZ;      // B*512
  float* istd = mean + B_ * D2_;  // B*512

  // 1) QKV projections
  qkv_gemm<<<dim3(N_ / 64, D_ / 64, B_ * 3), 256, 0, stream>>>(
      x, source, Wq, bq, Wk, bk, Wv, bv, Qg, Kg, Vg);
  // 2) attention -> msgC (channel = d*H + h)
  attn_kernel<<<dim3(N_ / 64, H_, B_), 256, 0, stream>>>(Qg, Kg, Vg, msgC);
  // 3) merge conv
  merge_gemm<<<dim3(N_ / 64, D_ / 64, B_), 256, 0, stream>>>(msgC, Wm, bm,
                                                             msg2);
  // 4) W1 on concat(x, message)
  w1_gemm<<<dim3(N_ / 64, D2_ / 64, B_), 256, 0, stream>>>(x, msg2, W1, b1,
                                                           h1);
  // 5) instance-norm stats
  stats_kernel<<<dim3(B_ * D2_), 256, 0, stream>>>(h1, mean, istd);
  // 6) W2 with fused norm+relu
  w2_gemm<<<dim3(N_ / 64, D_ / 64, B_), 256, 0, stream>>>(h1, mean, istd, W2,
                                                          b2, out);
}

// Round 3
// 520.192 us; speedup vs baseline: 2.6151x; 2.6151x over previous
//
#include <hip/hip_runtime.h>
#include <hip/hip_bf16.h>

// Problem constants
#define B_  8
#define D_  256
#define N_  2048
#define M_  2048
#define H_  4
#define DH_ 64
#define D2_ 512

typedef __attribute__((ext_vector_type(8))) short bf16x8;
typedef __attribute__((ext_vector_type(4))) short bf16x4;
typedef __attribute__((ext_vector_type(4))) float f32x4;

__device__ __forceinline__ unsigned short f2bf(float x) {
  union { float f; unsigned u; } c; c.f = x;
  return (unsigned short)((c.u + 0x7fffu + ((c.u >> 16) & 1u)) >> 16);
}

// ---------------------------------------------------------------------------
// Generic 64x64 f32 tiled-GEMM body (BM=64, BN=64, BK=16, 256 threads,
// 4x4 micro-tile per thread). A is [rows x KDIM] row-major, C ld = N_.
// ---------------------------------------------------------------------------
#define GEMM_BODY(KDIM, BEXPR)                                                  \
  __shared__ float As[16][68];                                                  \
  __shared__ float Bs[16][68];                                                  \
  const int t = threadIdx.x;                                                    \
  const int m0 = blockIdx.y * 64, n0 = blockIdx.x * 64;                         \
  const int tx = t & 15, ty = t >> 4;                                           \
  float acc[4][4] = {};                                                         \
  for (int k0 = 0; k0 < (KDIM); k0 += 16) {                                     \
    {                                                                           \
      int c = t & 15, r0 = t >> 4;                                              \
      _Pragma("unroll") for (int p = 0; p < 4; ++p) {                           \
        int mm = r0 + 16 * p;                                                   \
        As[c][mm] = A[(size_t)(m0 + mm) * (KDIM) + k0 + c];                     \
      }                                                                         \
    }                                                                           \
    {                                                                           \
      int nn = t & 63, r0 = t >> 6;                                             \
      _Pragma("unroll") for (int p = 0; p < 4; ++p) {                           \
        int kk = r0 + 4 * p;                                                    \
        int gk = k0 + kk;                                                       \
        int gn = n0 + nn;                                                       \
        Bs[kk][nn] = (BEXPR);                                                   \
      }                                                                         \
    }                                                                           \
    __syncthreads();                                                            \
    _Pragma("unroll") for (int kk = 0; kk < 16; ++kk) {                         \
      float4 av = *(const float4*)&As[kk][ty * 4];                              \
      float4 bv = *(const float4*)&Bs[kk][tx * 4];                              \
      acc[0][0] += av.x * bv.x; acc[0][1] += av.x * bv.y;                       \
      acc[0][2] += av.x * bv.z; acc[0][3] += av.x * bv.w;                       \
      acc[1][0] += av.y * bv.x; acc[1][1] += av.y * bv.y;                       \
      acc[1][2] += av.y * bv.z; acc[1][3] += av.y * bv.w;                       \
      acc[2][0] += av.z * bv.x; acc[2][1] += av.z * bv.y;                       \
      acc[2][2] += av.z * bv.z; acc[2][3] += av.z * bv.w;                       \
      acc[3][0] += av.w * bv.x; acc[3][1] += av.w * bv.y;                       \
      acc[3][2] += av.w * bv.z; acc[3][3] += av.w * bv.w;                       \
    }                                                                           \
    __syncthreads();                                                            \
  }                                                                             \
  _Pragma("unroll") for (int mi = 0; mi < 4; ++mi) {                            \
    int row = m0 + ty * 4 + mi;                                                 \
    float bb = bias[row];                                                       \
    float4 r;                                                                   \
    r.x = acc[mi][0] + bb; r.y = acc[mi][1] + bb;                               \
    r.z = acc[mi][2] + bb; r.w = acc[mi][3] + bb;                               \
    *(float4*)&Cdst[(size_t)row * N_ + n0 + tx * 4] = r;                        \
  }

// ---------------------------------------------------------------------------
// 1) QKV projection (f32 out, layout [B][h*64+d][N])
// ---------------------------------------------------------------------------
__global__ __launch_bounds__(256) void qkv_gemm(
    const float* __restrict__ x, const float* __restrict__ source,
    const float* __restrict__ Wq, const float* __restrict__ bq,
    const float* __restrict__ Wk, const float* __restrict__ bk,
    const float* __restrict__ Wv, const float* __restrict__ bv,
    float* __restrict__ Qg, float* __restrict__ Kg, float* __restrict__ Vg) {
  const int z = blockIdx.z;
  const int b = z / 3, w = z % 3;
  const float* A;
  const float* bias;
  const float* Bsrc;
  float* Cdst;
  if (w == 0) {
    A = Wq; bias = bq;
    Bsrc = x + (size_t)b * D_ * N_;
    Cdst = Qg + (size_t)b * D_ * N_;
  } else if (w == 1) {
    A = Wk; bias = bk;
    Bsrc = source + (size_t)b * D_ * M_;
    Cdst = Kg + (size_t)b * D_ * M_;
  } else {
    A = Wv; bias = bv;
    Bsrc = source + (size_t)b * D_ * M_;
    Cdst = Vg + (size_t)b * D_ * M_;
  }
  GEMM_BODY(256, Bsrc[(size_t)gk * N_ + gn])
}

// ---------------------------------------------------------------------------
// 1.5) Convert Q,K to transposed bf16 [bh][n][64]; V to bf16 [bh][64][m].
// grid: (32, 4, 8), 256 threads
// ---------------------------------------------------------------------------
__global__ __launch_bounds__(256) void qkv_to_bf16(
    const float* __restrict__ Qg, const float* __restrict__ Kg,
    const float* __restrict__ Vg, unsigned short* __restrict__ Qt,
    unsigned short* __restrict__ Kt, unsigned short* __restrict__ Vt) {
  __shared__ float T[64][65];
  const int t = threadIdx.x;
  const int n0 = blockIdx.x * 64, h = blockIdx.y, b = blockIdx.z;
  const int bh = b * H_ + h;
  const size_t gbase = (size_t)bh * 64 * N_;
  const int nn = t & 63, dd = t >> 6;
  const int dg = t & 7, nr = t >> 3;

  // ---- Q transpose ----
#pragma unroll
  for (int p = 0; p < 16; ++p)
    T[dd + 4 * p][nn] = Qg[gbase + (size_t)(dd + 4 * p) * N_ + n0 + nn];
  __syncthreads();
#pragma unroll
  for (int p = 0; p < 2; ++p) {
    int n = nr + 32 * p;
    union { bf16x8 v; unsigned short u[8]; } pk;
#pragma unroll
    for (int j = 0; j < 8; ++j) pk.u[j] = f2bf(T[dg * 8 + j][n]);
    *(bf16x8*)&Qt[gbase + (size_t)(n0 + n) * 64 + dg * 8] = pk.v;
  }
  __syncthreads();
  // ---- K transpose ----
#pragma unroll
  for (int p = 0; p < 16; ++p)
    T[dd + 4 * p][nn] = Kg[gbase + (size_t)(dd + 4 * p) * N_ + n0 + nn];
  __syncthreads();
#pragma unroll
  for (int p = 0; p < 2; ++p) {
    int n = nr + 32 * p;
    union { bf16x8 v; unsigned short u[8]; } pk;
#pragma unroll
    for (int j = 0; j < 8; ++j) pk.u[j] = f2bf(T[dg * 8 + j][n]);
    *(bf16x8*)&Kt[gbase + (size_t)(n0 + n) * 64 + dg * 8] = pk.v;
  }
  // ---- V straight convert ----
  const int mg = t & 15, dv = t >> 4;
#pragma unroll
  for (int p = 0; p < 4; ++p) {
    int d = dv + 16 * p;
    float4 v = *(const float4*)&Vg[gbase + (size_t)d * N_ + n0 + mg * 4];
    union { bf16x4 v4; unsigned short u[4]; } pk;
    pk.u[0] = f2bf(v.x); pk.u[1] = f2bf(v.y);
    pk.u[2] = f2bf(v.z); pk.u[3] = f2bf(v.w);
    *(bf16x4*)&Vt[gbase + (size_t)d * N_ + n0 + mg * 4] = pk.v4;
  }
}

// ---------------------------------------------------------------------------
// 2) MFMA flash attention. Block = 64 queries of one (b,h); 4 waves x 16 q.
//    Swapped QK^T: S^T = mfma(K, Q^T); softmax reduce = 15 in-reg + 2 shfl.
//    All LDS tiles XOR-swizzled by ((row&7)*8) on 8-elem groups.
// grid: (32, 4, 8), 256 threads
// ---------------------------------------------------------------------------
__global__ __launch_bounds__(256) void attn_mfma(
    const unsigned short* __restrict__ Qt,
    const unsigned short* __restrict__ Kt,
    const unsigned short* __restrict__ Vt, float* __restrict__ msgC) {
  __shared__ __align__(16) unsigned short Ks[64 * 64];  // [key][dh] swz
  __shared__ __align__(16) unsigned short Vs[64 * 64];  // [dh][key] swz
  __shared__ __align__(16) unsigned short Ps[64 * 64];  // [q][key]  swz
  const int t = threadIdx.x;
  const int lane = t & 63, wq = t >> 6;
  const int h = blockIdx.y, b = blockIdx.z;
  const int bh = b * H_ + h;
  const size_t base = (size_t)bh * 64 * N_;
  const int n00 = blockIdx.x * 64;
  const int lq = lane & 15, lg = lane >> 4;
  const int qrow = wq * 16 + lq;
  const int sw = (lq & 7) * 8;

  // Q fragments (B-operand), loaded once: lane holds Q[qrow][lg*8+i (+32)]
  bf16x8 qf0, qf1;
  {
    const unsigned short* qp = Qt + base + (size_t)(n00 + qrow) * 64 + lg * 8;
    qf0 = *(const bf16x8*)qp;
    qf1 = *(const bf16x8*)(qp + 32);
  }
  f32x4 o0 = {0.f, 0.f, 0.f, 0.f}, o1 = o0, o2 = o0, o3 = o0;
  float mrun = -3.0e38f, lrun = 0.f;
  const int sdg = (t & 7) * 8, srw = t >> 3;

  for (int m0 = 0; m0 < M_; m0 += 64) {
    // ---- stage K tile [key][dh] and V tile [dh][key] (bf16, swizzled) ----
#pragma unroll
    for (int p = 0; p < 2; ++p) {
      int r = srw + 32 * p;
      int wsw = (r & 7) * 8;
      *(bf16x8*)&Ks[r * 64 + (sdg ^ wsw)] =
          *(const bf16x8*)(Kt + base + (size_t)(m0 + r) * 64 + sdg);
      *(bf16x8*)&Vs[r * 64 + (sdg ^ wsw)] =
          *(const bf16x8*)(Vt + base + (size_t)r * N_ + m0 + sdg);
    }
    __syncthreads();

    // ---- S^T = K · Q^T  (rows = keys, cols = queries) ----
    f32x4 s0 = {0.f, 0.f, 0.f, 0.f}, s1 = s0, s2 = s0, s3 = s0;
#pragma unroll
    for (int kt = 0; kt < 2; ++kt) {
      const int dh0 = (lg * 8 + 32 * kt) ^ sw;
      const bf16x8 qb = kt ? qf1 : qf0;
      s0 = __builtin_amdgcn_mfma_f32_16x16x32_bf16(
          *(const bf16x8*)&Ks[lq * 64 + dh0], qb, s0, 0, 0, 0);
      s1 = __builtin_amdgcn_mfma_f32_16x16x32_bf16(
          *(const bf16x8*)&Ks[(16 + lq) * 64 + dh0], qb, s1, 0, 0, 0);
      s2 = __builtin_amdgcn_mfma_f32_16x16x32_bf16(
          *(const bf16x8*)&Ks[(32 + lq) * 64 + dh0], qb, s2, 0, 0, 0);
      s3 = __builtin_amdgcn_mfma_f32_16x16x32_bf16(
          *(const bf16x8*)&Ks[(48 + lq) * 64 + dh0], qb, s3, 0, 0, 0);
    }

    // ---- online softmax (lane owns query qrow; keys 16kf+4lg+r) ----
    float sv[16];
#pragma unroll
    for (int r = 0; r < 4; ++r) {
      sv[0 + r]  = s0[r] * 0.125f;
      sv[4 + r]  = s1[r] * 0.125f;
      sv[8 + r]  = s2[r] * 0.125f;
      sv[12 + r] = s3[r] * 0.125f;
    }
    float tm = sv[0];
#pragma unroll
    for (int i = 1; i < 16; ++i) tm = fmaxf(tm, sv[i]);
    tm = fmaxf(tm, __shfl_xor(tm, 16));
    tm = fmaxf(tm, __shfl_xor(tm, 32));
    const float Mn = fmaxf(mrun, tm);
    const float scl = __expf(mrun - Mn);
    float ls = 0.f;
#pragma unroll
    for (int i = 0; i < 16; ++i) {
      sv[i] = __expf(sv[i] - Mn);
      ls += sv[i];
    }
    ls += __shfl_xor(ls, 16);
    ls += __shfl_xor(ls, 32);
    lrun = lrun * scl + ls;
    mrun = Mn;
    o0 *= scl; o1 *= scl; o2 *= scl; o3 *= scl;

    // ---- P^T to LDS (rows = q, cols = key), bf16 ----
#pragma unroll
    for (int kf = 0; kf < 4; ++kf) {
      union { bf16x4 v; unsigned short u[4]; } pk;
#pragma unroll
      for (int r = 0; r < 4; ++r) pk.u[r] = f2bf(sv[kf * 4 + r]);
      const int kb = 16 * kf + 4 * lg;
      *(bf16x4*)&Ps[qrow * 64 + (kb ^ sw)] = pk.v;
    }
    asm volatile("s_waitcnt lgkmcnt(0)" ::: "memory");

    // ---- O^T += V^T · P^T ----
#pragma unroll
    for (int kt = 0; kt < 2; ++kt) {
      const int k0 = (lg * 8 + 32 * kt) ^ sw;
      const bf16x8 pb = *(const bf16x8*)&Ps[qrow * 64 + k0];
      o0 = __builtin_amdgcn_mfma_f32_16x16x32_bf16(
          *(const bf16x8*)&Vs[lq * 64 + k0], pb, o0, 0, 0, 0);
      o1 = __builtin_amdgcn_mfma_f32_16x16x32_bf16(
          *(const bf16x8*)&Vs[(16 + lq) * 64 + k0], pb, o1, 0, 0, 0);
      o2 = __builtin_amdgcn_mfma_f32_16x16x32_bf16(
          *(const bf16x8*)&Vs[(32 + lq) * 64 + k0], pb, o2, 0, 0, 0);
      o3 = __builtin_amdgcn_mfma_f32_16x16x32_bf16(
          *(const bf16x8*)&Vs[(48 + lq) * 64 + k0], pb, o3, 0, 0, 0);
    }
    __syncthreads();
  }

  // ---- write msgC[b][c = dh*H + h][n], dh = 16*df + 4*lg + r ----
  const float inv = 1.f / lrun;
  const size_t obase = (size_t)b * D_ * N_ + (size_t)(n00 + qrow);
#pragma unroll
  for (int r = 0; r < 4; ++r) {
    msgC[obase + (size_t)((0  + 4 * lg + r) * H_ + h) * N_] = o0[r] * inv;
    msgC[obase + (size_t)((16 + 4 * lg + r) * H_ + h) * N_] = o1[r] * inv;
    msgC[obase + (size_t)((32 + 4 * lg + r) * H_ + h) * N_] = o2[r] * inv;
    msgC[obase + (size_t)((48 + 4 * lg + r) * H_ + h) * N_] = o3[r] * inv;
  }
}

// ---------------------------------------------------------------------------
// 3) merge conv
// ---------------------------------------------------------------------------
__global__ __launch_bounds__(256) void merge_gemm(
    const float* __restrict__ msgC, const float* __restrict__ Wm,
    const float* __restrict__ bm, float* __restrict__ msg2) {
  const int b = blockIdx.z;
  const float* A = Wm;
  const float* bias = bm;
  const float* Bsrc = msgC + (size_t)b * D_ * N_;
  float* Cdst = msg2 + (size_t)b * D_ * N_;
  GEMM_BODY(256, Bsrc[(size_t)gk * N_ + gn])
}

// ---------------------------------------------------------------------------
// 4) W1 on virtual concat(x, message)
// ---------------------------------------------------------------------------
__global__ __launch_bounds__(256) void w1_gemm(
    const float* __restrict__ x, const float* __restrict__ msg2,
    const float* __restrict__ W1, const float* __restrict__ b1,
    float* __restrict__ h1) {
  const int b = blockIdx.z;
  const float* A = W1;
  const float* bias = b1;
  const float* xb = x + (size_t)b * D_ * N_;
  const float* msgb = msg2 + (size_t)b * D_ * N_;
  float* Cdst = h1 + (size_t)b * D2_ * N_;
  GEMM_BODY(512, (gk < 256 ? xb[(size_t)gk * N_ + gn]
                           : msgb[(size_t)(gk - 256) * N_ + gn]))
}

// ---------------------------------------------------------------------------
// 5) InstanceNorm stats
// ---------------------------------------------------------------------------
__global__ __launch_bounds__(256) void stats_kernel(
    const float* __restrict__ h1, float* __restrict__ mean,
    float* __restrict__ istd) {
  const int row = blockIdx.x;
  const float* p = h1 + (size_t)row * N_;
  float s = 0.f, ss = 0.f;
  for (int i = threadIdx.x; i < N_; i += 256) {
    float v = p[i];
    s += v;
    ss += v * v;
  }
#pragma unroll
  for (int o = 1; o < 64; o <<= 1) {
    s += __shfl_xor(s, o);
    ss += __shfl_xor(ss, o);
  }
  __shared__ float red[2][4];
  const int w = threadIdx.x >> 6;
  if ((threadIdx.x & 63) == 0) {
    red[0][w] = s;
    red[1][w] = ss;
  }
  __syncthreads();
  if (threadIdx.x == 0) {
    float S = red[0][0] + red[0][1] + red[0][2] + red[0][3];
    float SS = red[1][0] + red[1][1] + red[1][2] + red[1][3];
    float mn = S * (1.f / N_);
    float var = SS * (1.f / N_) - mn * mn;
    mean[row] = mn;
    istd[row] = rsqrtf(var + 1e-5f);
  }
}

// ---------------------------------------------------------------------------
// 6) W2 with fused instnorm+relu B loader
// ---------------------------------------------------------------------------
__global__ __launch_bounds__(256) void w2_gemm(
    const float* __restrict__ h1, const float* __restrict__ mean,
    const float* __restrict__ istd, const float* __restrict__ W2,
    const float* __restrict__ b2, float* __restrict__ out) {
  const int b = blockIdx.z;
  const float* A = W2;
  const float* bias = b2;
  const float* Bsrc = h1 + (size_t)b * D2_ * N_;
  const float* meanp = mean + b * D2_;
  const float* istdp = istd + b * D2_;
  float* Cdst = out + (size_t)b * D_ * N_;
  GEMM_BODY(512,
            fmaxf((Bsrc[(size_t)gk * N_ + gn] - meanp[gk]) * istdp[gk], 0.f))
}

// ---------------------------------------------------------------------------
extern "C" void kernel_launch(void* const* d_in, const int* in_sizes, int n_in,
                              void* d_out, int out_size, void* d_ws,
                              size_t ws_size, hipStream_t stream) {
  const float* x = (const float*)d_in[0];
  const float* source = (const float*)d_in[1];
  const float* Wq = (const float*)d_in[2];
  const float* bq = (const float*)d_in[3];
  const float* Wk = (const float*)d_in[4];
  const float* bk = (const float*)d_in[5];
  const float* Wv = (const float*)d_in[6];
  const float* bv = (const float*)d_in[7];
  const float* Wm = (const float*)d_in[8];
  const float* bm = (const float*)d_in[9];
  const float* W1 = (const float*)d_in[10];
  const float* b1 = (const float*)d_in[11];
  const float* W2 = (const float*)d_in[12];
  const float* b2 = (const float*)d_in[13];
  float* out = (float*)d_out;

  float* ws = (float*)d_ws;
  const size_t SZ = (size_t)B_ * D_ * N_;  // 4,194,304
  float* Qg = ws;
  float* Kg = Qg + SZ;
  float* Vg = Kg + SZ;
  float* msgC = Vg + SZ;
  float* msg2 = msgC + SZ;
  float* h1 = msg2 + SZ;          // 2*SZ floats
  float* mean = h1 + 2 * SZ;
  float* istd = mean + B_ * D2_;
  // bf16 Q/K/V transposed buffers live inside h1's region (h1 not yet live:
  // written by w1_gemm AFTER attention is done reading these).
  unsigned short* Qt = (unsigned short*)h1;
  unsigned short* Kt = Qt + SZ;  // SZ bf16 elems each
  unsigned short* Vt = Kt + SZ;

  qkv_gemm<<<dim3(N_ / 64, D_ / 64, B_ * 3), 256, 0, stream>>>(
      x, source, Wq, bq, Wk, bk, Wv, bv, Qg, Kg, Vg);
  qkv_to_bf16<<<dim3(N_ / 64, H_, B_), 256, 0, stream>>>(Qg, Kg, Vg, Qt, Kt,
                                                         Vt);
  attn_mfma<<<dim3(N_ / 64, H_, B_), 256, 0, stream>>>(Qt, Kt, Vt, msgC);
  merge_gemm<<<dim3(N_ / 64, D_ / 64, B_), 256, 0, stream>>>(msgC, Wm, bm,
                                                             msg2);
  w1_gemm<<<dim3(N_ / 64, D2_ / 64, B_), 256, 0, stream>>>(x, msg2, W1, b1,
                                                           h1);
  stats_kernel<<<dim3(B_ * D2_), 256, 0, stream>>>(h1, mean, istd);
  w2_gemm<<<dim3(N_ / 64, D_ / 64, B_), 256, 0, stream>>>(h1, mean, istd, W2,
                                                          b2, out);
}

// Round 5
// 294.897 us; speedup vs baseline: 4.6130x; 1.7640x over previous
//
#include <hip/hip_runtime.h>
#include <hip/hip_bf16.h>

// Problem constants
#define B_  8
#define D_  256
#define N_  2048
#define M_  2048
#define H_  4
#define DH_ 64
#define D2_ 512

typedef unsigned short ushort_t;
typedef __attribute__((ext_vector_type(8))) short bf16x8;
typedef __attribute__((ext_vector_type(4))) short bf16x4;
typedef __attribute__((ext_vector_type(4))) float f32x4;

__device__ __forceinline__ ushort_t f2bf(float x) {
  union { float f; unsigned u; } c; c.f = x;
  return (ushort_t)((c.u + 0x7fffu + ((c.u >> 16) & 1u)) >> 16);
}
__device__ __forceinline__ float bf2f(ushort_t h) {
  union { unsigned u; float f; } c; c.u = ((unsigned)h) << 16; return c.f;
}

// ---------------------------------------------------------------------------
// MFMA GEMM core: 128x128 tile, 4 waves (2x2), per-wave 64x64 (4x4 frags).
// A bf16 [O][K] row-major; Bt bf16 [N][LDB] (k fastest). No LDS: fragments
// stream straight from global (operands are L2-resident).
// D[o][n]: o = m0 + 16*fm + 4*lg + r, n = n0 + 16*fn + lq.
// ---------------------------------------------------------------------------
template <int K, int LDB>
__device__ __forceinline__ void mfma_core(const ushort_t* __restrict__ Arow,
                                          const ushort_t* __restrict__ Brow,
                                          f32x4 acc[4][4], int lg) {
#pragma unroll 2
  for (int k0 = 0; k0 < K; k0 += 32) {
    bf16x8 af[4], bfr[4];
#pragma unroll
    for (int f = 0; f < 4; ++f)
      af[f] = *(const bf16x8*)&Arow[(size_t)16 * f * K + k0 + lg * 8];
#pragma unroll
    for (int f = 0; f < 4; ++f)
      bfr[f] = *(const bf16x8*)&Brow[(size_t)16 * f * LDB + k0 + lg * 8];
#pragma unroll
    for (int fm = 0; fm < 4; ++fm)
#pragma unroll
      for (int fn = 0; fn < 4; ++fn)
        acc[fm][fn] = __builtin_amdgcn_mfma_f32_16x16x32_bf16(
            af[fm], bfr[fn], acc[fm][fn], 0, 0, 0);
  }
}

#define GEMM_PREAMBLE()                                   \
  const int t = threadIdx.x, lane = t & 63, wv = t >> 6;  \
  const int wm = wv >> 1, wn = wv & 1;                    \
  const int lq = lane & 15, lg = lane >> 4;               \
  const int m0 = blockIdx.y * 128 + wm * 64;              \
  const int n0 = blockIdx.x * 128 + wn * 64;              \
  f32x4 acc[4][4];                                        \
  _Pragma("unroll") for (int i = 0; i < 4; ++i)           \
  _Pragma("unroll") for (int j = 0; j < 4; ++j)           \
      acc[i][j] = (f32x4){0.f, 0.f, 0.f, 0.f};

// ---------------------------------------------------------------------------
// 0) Convert weights to bf16. Wm gets its COLUMNS permuted to head-major
//    (c' = h*64+dh  <-  c = dh*4+h) so attention can write msgT head-major.
// grid: 2560 x 256
// ---------------------------------------------------------------------------
__global__ __launch_bounds__(256) void prep_weights(
    const float* __restrict__ Wq, const float* __restrict__ Wk,
    const float* __restrict__ Wv, const float* __restrict__ Wm,
    const float* __restrict__ W1, const float* __restrict__ W2,
    ushort_t* __restrict__ Wqb, ushort_t* __restrict__ Wkb,
    ushort_t* __restrict__ Wvb, ushort_t* __restrict__ Wmb,
    ushort_t* __restrict__ W1b, ushort_t* __restrict__ W2b) {
  const int idx = blockIdx.x * 256 + threadIdx.x;
  if (idx < 65536) {
    Wqb[idx] = f2bf(Wq[idx]);
  } else if (idx < 131072) {
    int j = idx - 65536; Wkb[j] = f2bf(Wk[j]);
  } else if (idx < 196608) {
    int j = idx - 131072; Wvb[j] = f2bf(Wv[j]);
  } else if (idx < 262144) {
    int j = idx - 196608;
    int e = j >> 8, cp = j & 255;
    int h = cp >> 6, dh = cp & 63;
    Wmb[j] = f2bf(Wm[e * 256 + dh * 4 + h]);
  } else if (idx < 524288) {
    int j = idx - 262144; W1b[j] = f2bf(W1[j]);
  } else if (idx < 655360) {
    int j = idx - 524288; W2b[j] = f2bf(W2[j]);
  }
}

// ---------------------------------------------------------------------------
// 0.5) Transpose x -> cat_t[:, :256] (ld 512) and source -> st (ld 256), bf16.
// grid: (32, 4, 16) ; z: b = z&7, which = z>>3
// ---------------------------------------------------------------------------
__global__ __launch_bounds__(256) void transpose_in(
    const float* __restrict__ x, const float* __restrict__ source,
    ushort_t* __restrict__ cat_t, ushort_t* __restrict__ st) {
  __shared__ float T[64][65];
  const int t = threadIdx.x;
  const int b = blockIdx.z & 7, which = blockIdx.z >> 3;
  const float* sb = (which ? source : x) + (size_t)b * D_ * N_;
  ushort_t* dst = which ? st + (size_t)b * N_ * 256 : cat_t + (size_t)b * N_ * 512;
  const int ldc = which ? 256 : 512;
  const int d0 = blockIdx.y * 64, n0 = blockIdx.x * 64;
  const int nn = t & 63, dd = t >> 6;
#pragma unroll
  for (int p = 0; p < 16; ++p)
    T[dd + 4 * p][nn] = sb[(size_t)(d0 + dd + 4 * p) * N_ + n0 + nn];
  __syncthreads();
  const int dg = t & 7, nr = t >> 3;
#pragma unroll
  for (int p = 0; p < 2; ++p) {
    int n = nr + 32 * p;
    union { bf16x8 v; ushort_t u[8]; } pk;
#pragma unroll
    for (int j = 0; j < 8; ++j) pk.u[j] = f2bf(T[dg * 8 + j][n]);
    *(bf16x8*)&dst[(size_t)(n0 + n) * ldc + d0 + dg * 8] = pk.v;
  }
}

// ---------------------------------------------------------------------------
// 1a) Q projection: Qt[bh][n][64] bf16.  grid (16, 2, 8)
// ---------------------------------------------------------------------------
__global__ __launch_bounds__(256) void q_mfma(
    const ushort_t* __restrict__ Wqb, const float* __restrict__ bq,
    const ushort_t* __restrict__ cat_t, ushort_t* __restrict__ Qt) {
  GEMM_PREAMBLE()
  const int b = blockIdx.z;
  const ushort_t* Arow = Wqb + (size_t)(m0 + lq) * 256;
  const ushort_t* Brow = cat_t + ((size_t)b * N_ + n0 + lq) * 512;
  mfma_core<256, 512>(Arow, Brow, acc, lg);
  ushort_t* Qb = Qt + (size_t)b * 4 * N_ * 64;
#pragma unroll
  for (int fm = 0; fm < 4; ++fm) {
    const int o0 = m0 + 16 * fm + 4 * lg;
    const int hh = o0 >> 6, dl = o0 & 63;
    float bb[4];
#pragma unroll
    for (int r = 0; r < 4; ++r) bb[r] = bq[o0 + r];
#pragma unroll
    for (int fn = 0; fn < 4; ++fn) {
      const int n = n0 + 16 * fn + lq;
      union { bf16x4 v; ushort_t u[4]; } pk;
#pragma unroll
      for (int r = 0; r < 4; ++r) pk.u[r] = f2bf(acc[fm][fn][r] + bb[r]);
      *(bf16x4*)&Qb[((size_t)hh * N_ + n) * 64 + dl] = pk.v;
    }
  }
}

// ---------------------------------------------------------------------------
// 1b) K,V projections from source: Kt[bh][n][64]; Vt[bh][64][m].
// grid (16, 2, 16) ; z: b = z>>1, w = z&1 (0=K, 1=V)
// ---------------------------------------------------------------------------
__global__ __launch_bounds__(256) void kv_mfma(
    const ushort_t* __restrict__ Wkb, const ushort_t* __restrict__ Wvb,
    const float* __restrict__ bk, const float* __restrict__ bv,
    const ushort_t* __restrict__ st, ushort_t* __restrict__ Kt,
    ushort_t* __restrict__ Vt) {
  const int b = blockIdx.z >> 1, w = blockIdx.z & 1;
  GEMM_PREAMBLE()
  const ushort_t* A = w ? Wvb : Wkb;
  const float* bias = w ? bv : bk;
  const ushort_t* Arow = A + (size_t)(m0 + lq) * 256;
  const ushort_t* Brow = st + ((size_t)b * N_ + n0 + lq) * 256;
  mfma_core<256, 256>(Arow, Brow, acc, lg);
  if (w == 0) {
    ushort_t* Kb = Kt + (size_t)b * 4 * N_ * 64;
#pragma unroll
    for (int fm = 0; fm < 4; ++fm) {
      const int o0 = m0 + 16 * fm + 4 * lg;
      const int hh = o0 >> 6, dl = o0 & 63;
      float bb[4];
#pragma unroll
      for (int r = 0; r < 4; ++r) bb[r] = bias[o0 + r];
#pragma unroll
      for (int fn = 0; fn < 4; ++fn) {
        const int n = n0 + 16 * fn + lq;
        union { bf16x4 v; ushort_t u[4]; } pk;
#pragma unroll
        for (int r = 0; r < 4; ++r) pk.u[r] = f2bf(acc[fm][fn][r] + bb[r]);
        *(bf16x4*)&Kb[((size_t)hh * N_ + n) * 64 + dl] = pk.v;
      }
    }
  } else {
    ushort_t* Vb = Vt + (size_t)b * 256 * N_;
#pragma unroll
    for (int fm = 0; fm < 4; ++fm) {
      const int o0 = m0 + 16 * fm + 4 * lg;
      float bb[4];
#pragma unroll
      for (int r = 0; r < 4; ++r) bb[r] = bias[o0 + r];
#pragma unroll
      for (int fn = 0; fn < 4; ++fn) {
        const int n = n0 + 16 * fn + lq;
#pragma unroll
        for (int r = 0; r < 4; ++r)
          Vb[(size_t)(o0 + r) * N_ + n] = f2bf(acc[fm][fn][r] + bb[r]);
      }
    }
  }
}

// ---------------------------------------------------------------------------
// 2) MFMA flash attention (unchanged core). Writes msgT[b][n][h*64+dh] bf16.
// grid: (32, 4, 8), 256 threads
// ---------------------------------------------------------------------------
__global__ __launch_bounds__(256) void attn_mfma(
    const ushort_t* __restrict__ Qt, const ushort_t* __restrict__ Kt,
    const ushort_t* __restrict__ Vt, ushort_t* __restrict__ msgT) {
  __shared__ __align__(16) ushort_t Ks[64 * 64];  // [key][dh] swz
  __shared__ __align__(16) ushort_t Vs[64 * 64];  // [dh][key] swz
  __shared__ __align__(16) ushort_t Ps[64 * 64];  // [q][key]  swz
  const int t = threadIdx.x;
  const int lane = t & 63, wq = t >> 6;
  const int h = blockIdx.y, b = blockIdx.z;
  const int bh = b * H_ + h;
  const size_t base = (size_t)bh * 64 * N_;
  const int n00 = blockIdx.x * 64;
  const int lq = lane & 15, lg = lane >> 4;
  const int qrow = wq * 16 + lq;
  const int sw = (lq & 7) * 8;

  bf16x8 qf0, qf1;
  {
    const ushort_t* qp = Qt + base + (size_t)(n00 + qrow) * 64 + lg * 8;
    qf0 = *(const bf16x8*)qp;
    qf1 = *(const bf16x8*)(qp + 32);
  }
  f32x4 o0 = {0.f, 0.f, 0.f, 0.f}, o1 = o0, o2 = o0, o3 = o0;
  float mrun = -3.0e38f, lrun = 0.f;
  const int sdg = (t & 7) * 8, srw = t >> 3;

  for (int m0 = 0; m0 < M_; m0 += 64) {
#pragma unroll
    for (int p = 0; p < 2; ++p) {
      int r = srw + 32 * p;
      int wsw = (r & 7) * 8;
      *(bf16x8*)&Ks[r * 64 + (sdg ^ wsw)] =
          *(const bf16x8*)(Kt + base + (size_t)(m0 + r) * 64 + sdg);
      *(bf16x8*)&Vs[r * 64 + (sdg ^ wsw)] =
          *(const bf16x8*)(Vt + base + (size_t)r * N_ + m0 + sdg);
    }
    __syncthreads();

    f32x4 s0 = {0.f, 0.f, 0.f, 0.f}, s1 = s0, s2 = s0, s3 = s0;
#pragma unroll
    for (int kt = 0; kt < 2; ++kt) {
      const int dh0 = (lg * 8 + 32 * kt) ^ sw;
      const bf16x8 qb = kt ? qf1 : qf0;
      s0 = __builtin_amdgcn_mfma_f32_16x16x32_bf16(
          *(const bf16x8*)&Ks[lq * 64 + dh0], qb, s0, 0, 0, 0);
      s1 = __builtin_amdgcn_mfma_f32_16x16x32_bf16(
          *(const bf16x8*)&Ks[(16 + lq) * 64 + dh0], qb, s1, 0, 0, 0);
      s2 = __builtin_amdgcn_mfma_f32_16x16x32_bf16(
          *(const bf16x8*)&Ks[(32 + lq) * 64 + dh0], qb, s2, 0, 0, 0);
      s3 = __builtin_amdgcn_mfma_f32_16x16x32_bf16(
          *(const bf16x8*)&Ks[(48 + lq) * 64 + dh0], qb, s3, 0, 0, 0);
    }

    float sv[16];
#pragma unroll
    for (int r = 0; r < 4; ++r) {
      sv[0 + r]  = s0[r] * 0.125f;
      sv[4 + r]  = s1[r] * 0.125f;
      sv[8 + r]  = s2[r] * 0.125f;
      sv[12 + r] = s3[r] * 0.125f;
    }
    float tm = sv[0];
#pragma unroll
    for (int i = 1; i < 16; ++i) tm = fmaxf(tm, sv[i]);
    tm = fmaxf(tm, __shfl_xor(tm, 16));
    tm = fmaxf(tm, __shfl_xor(tm, 32));
    const float Mn = fmaxf(mrun, tm);
    const float scl = __expf(mrun - Mn);
    float ls = 0.f;
#pragma unroll
    for (int i = 0; i < 16; ++i) {
      sv[i] = __expf(sv[i] - Mn);
      ls += sv[i];
    }
    ls += __shfl_xor(ls, 16);
    ls += __shfl_xor(ls, 32);
    lrun = lrun * scl + ls;
    mrun = Mn;
    o0 *= scl; o1 *= scl; o2 *= scl; o3 *= scl;

#pragma unroll
    for (int kf = 0; kf < 4; ++kf) {
      union { bf16x4 v; ushort_t u[4]; } pk;
#pragma unroll
      for (int r = 0; r < 4; ++r) pk.u[r] = f2bf(sv[kf * 4 + r]);
      const int kb = 16 * kf + 4 * lg;
      *(bf16x4*)&Ps[qrow * 64 + (kb ^ sw)] = pk.v;
    }
    asm volatile("s_waitcnt lgkmcnt(0)" ::: "memory");

#pragma unroll
    for (int kt = 0; kt < 2; ++kt) {
      const int k0 = (lg * 8 + 32 * kt) ^ sw;
      const bf16x8 pb = *(const bf16x8*)&Ps[qrow * 64 + k0];
      o0 = __builtin_amdgcn_mfma_f32_16x16x32_bf16(
          *(const bf16x8*)&Vs[lq * 64 + k0], pb, o0, 0, 0, 0);
      o1 = __builtin_amdgcn_mfma_f32_16x16x32_bf16(
          *(const bf16x8*)&Vs[(16 + lq) * 64 + k0], pb, o1, 0, 0, 0);
      o2 = __builtin_amdgcn_mfma_f32_16x16x32_bf16(
          *(const bf16x8*)&Vs[(32 + lq) * 64 + k0], pb, o2, 0, 0, 0);
      o3 = __builtin_amdgcn_mfma_f32_16x16x32_bf16(
          *(const bf16x8*)&Vs[(48 + lq) * 64 + k0], pb, o3, 0, 0, 0);
    }
    __syncthreads();
  }

  // ---- write msgT[b][n][h*64 + dh] bf16 (head-major; Wm cols permuted) ----
  const float inv = 1.f / lrun;
  ushort_t* mp = msgT + ((size_t)b * N_ + n00 + qrow) * 256 + h * 64;
  {
    union { bf16x4 v; ushort_t u[4]; } pk;
#pragma unroll
    for (int r = 0; r < 4; ++r) pk.u[r] = f2bf(o0[r] * inv);
    *(bf16x4*)&mp[0 + 4 * lg] = pk.v;
#pragma unroll
    for (int r = 0; r < 4; ++r) pk.u[r] = f2bf(o1[r] * inv);
    *(bf16x4*)&mp[16 + 4 * lg] = pk.v;
#pragma unroll
    for (int r = 0; r < 4; ++r) pk.u[r] = f2bf(o2[r] * inv);
    *(bf16x4*)&mp[32 + 4 * lg] = pk.v;
#pragma unroll
    for (int r = 0; r < 4; ++r) pk.u[r] = f2bf(o3[r] * inv);
    *(bf16x4*)&mp[48 + 4 * lg] = pk.v;
  }
}

// ---------------------------------------------------------------------------
// 3) merge: msg2^T -> cat_t[:, 256:] (ld 512).  grid (16, 2, 8)
// ---------------------------------------------------------------------------
__global__ __launch_bounds__(256) void merge_mfma(
    const ushort_t* __restrict__ Wmb, const float* __restrict__ bm,
    const ushort_t* __restrict__ msgT, ushort_t* __restrict__ cat_t) {
  GEMM_PREAMBLE()
  const int b = blockIdx.z;
  const ushort_t* Arow = Wmb + (size_t)(m0 + lq) * 256;
  const ushort_t* Brow = msgT + ((size_t)b * N_ + n0 + lq) * 256;
  mfma_core<256, 256>(Arow, Brow, acc, lg);
  ushort_t* ob = cat_t + (size_t)b * N_ * 512 + 256;
#pragma unroll
  for (int fm = 0; fm < 4; ++fm) {
    const int o0 = m0 + 16 * fm + 4 * lg;
    float bb[4];
#pragma unroll
    for (int r = 0; r < 4; ++r) bb[r] = bm[o0 + r];
#pragma unroll
    for (int fn = 0; fn < 4; ++fn) {
      const int n = n0 + 16 * fn + lq;
      union { bf16x4 v; ushort_t u[4]; } pk;
#pragma unroll
      for (int r = 0; r < 4; ++r) pk.u[r] = f2bf(acc[fm][fn][r] + bb[r]);
      *(bf16x4*)&ob[(size_t)n * 512 + o0] = pk.v;
    }
  }
}

// ---------------------------------------------------------------------------
// 4) W1: h1^T = (W1 @ cat)^T -> h1t[b][n][512] bf16.  grid (16, 4, 8)
// ---------------------------------------------------------------------------
__global__ __launch_bounds__(256) void w1_mfma(
    const ushort_t* __restrict__ W1b, const float* __restrict__ b1,
    const ushort_t* __restrict__ cat_t, ushort_t* __restrict__ h1t) {
  GEMM_PREAMBLE()
  const int b = blockIdx.z;
  const ushort_t* Arow = W1b + (size_t)(m0 + lq) * 512;
  const ushort_t* Brow = cat_t + ((size_t)b * N_ + n0 + lq) * 512;
  mfma_core<512, 512>(Arow, Brow, acc, lg);
  ushort_t* ob = h1t + (size_t)b * N_ * 512;
#pragma unroll
  for (int fm = 0; fm < 4; ++fm) {
    const int o0 = m0 + 16 * fm + 4 * lg;
    float bb[4];
#pragma unroll
    for (int r = 0; r < 4; ++r) bb[r] = b1[o0 + r];
#pragma unroll
    for (int fn = 0; fn < 4; ++fn) {
      const int n = n0 + 16 * fn + lq;
      union { bf16x4 v; ushort_t u[4]; } pk;
#pragma unroll
      for (int r = 0; r < 4; ++r) pk.u[r] = f2bf(acc[fm][fn][r] + bb[r]);
      *(bf16x4*)&ob[(size_t)n * 512 + o0] = pk.v;
    }
  }
}

// ---------------------------------------------------------------------------
// 5) InstanceNorm stats on h1t
// ---------------------------------------------------------------------------
__global__ __launch_bounds__(256) void zero_stats(float* __restrict__ s) {
  s[blockIdx.x * 256 + threadIdx.x] = 0.f;  // grid 32 -> 8192 floats
}

// grid (8 nchunk, 8 cchunk, 8 b)
__global__ __launch_bounds__(256) void stats_partial(
    const ushort_t* __restrict__ h1t, float* __restrict__ ssum,
    float* __restrict__ ssq) {
  const int t = threadIdx.x;
  const int c = blockIdx.y * 64 + (t & 63);
  const int b = blockIdx.z;
  const int nbase = blockIdx.x * 256 + (t >> 6) * 64;
  const ushort_t* p = h1t + (size_t)b * N_ * 512;
  float s = 0.f, ss = 0.f;
  for (int i = 0; i < 64; ++i) {
    float v = bf2f(p[(size_t)(nbase + i) * 512 + c]);
    s += v; ss += v * v;
  }
  __shared__ float rs[4][64], rq[4][64];
  const int wv = t >> 6;
  rs[wv][t & 63] = s; rq[wv][t & 63] = ss;
  __syncthreads();
  if (t < 64) {
    float S = rs[0][t] + rs[1][t] + rs[2][t] + rs[3][t];
    float Q = rq[0][t] + rq[1][t] + rq[2][t] + rq[3][t];
    atomicAdd(&ssum[b * 512 + blockIdx.y * 64 + t], S);
    atomicAdd(&ssq[b * 512 + blockIdx.y * 64 + t], Q);
  }
}

__global__ __launch_bounds__(256) void finalize_stats(
    const float* __restrict__ ssum, const float* __restrict__ ssq,
    float* __restrict__ mean, float* __restrict__ istd) {
  const int i = blockIdx.x * 256 + threadIdx.x;  // grid 16 -> 4096
  float mn = ssum[i] * (1.f / N_);
  float var = ssq[i] * (1.f / N_) - mn * mn;
  mean[i] = mn;
  istd[i] = rsqrtf(var + 1e-5f);
}

// ---------------------------------------------------------------------------
// 6) normalize+relu: h1n = relu((h1t - mean) * istd) bf16.  grid 4096
// ---------------------------------------------------------------------------
__global__ __launch_bounds__(256) void normalize_h1(
    const ushort_t* __restrict__ h1t, const float* __restrict__ mean,
    const float* __restrict__ istd, ushort_t* __restrict__ h1n) {
  const size_t ci = (size_t)blockIdx.x * 256 + threadIdx.x;
  const size_t basei = ci * 8;
  const int c0 = (int)(basei & 511);
  const size_t row = basei >> 9;  // b*N + n
  const int b = (int)(row >> 11);
  const float* mp = mean + b * 512 + c0;
  const float* ip = istd + b * 512 + c0;
  union { bf16x8 v; ushort_t u[8]; } in, outv;
  in.v = *(const bf16x8*)&h1t[basei];
#pragma unroll
  for (int j = 0; j < 8; ++j) {
    float g = (bf2f(in.u[j]) - mp[j]) * ip[j];
    outv.u[j] = f2bf(fmaxf(g, 0.f));
  }
  *(bf16x8*)&h1n[basei] = outv.v;
}

// ---------------------------------------------------------------------------
// 7) W2: out = W2 @ h1n + b2, f32 [b][256][N].  grid (16, 2, 8)
// ---------------------------------------------------------------------------
__global__ __launch_bounds__(256) void w2_mfma(
    const ushort_t* __restrict__ W2b, const float* __restrict__ b2,
    const ushort_t* __restrict__ h1n, float* __restrict__ out) {
  GEMM_PREAMBLE()
  const int b = blockIdx.z;
  const ushort_t* Arow = W2b + (size_t)(m0 + lq) * 512;
  const ushort_t* Brow = h1n + ((size_t)b * N_ + n0 + lq) * 512;
  mfma_core<512, 512>(Arow, Brow, acc, lg);
  float* ob = out + (size_t)b * D_ * N_;
#pragma unroll
  for (int fm = 0; fm < 4; ++fm) {
    const int o0 = m0 + 16 * fm + 4 * lg;
    float bb[4];
#pragma unroll
    for (int r = 0; r < 4; ++r) bb[r] = b2[o0 + r];
#pragma unroll
    for (int fn = 0; fn < 4; ++fn) {
      const int n = n0 + 16 * fn + lq;
#pragma unroll
      for (int r = 0; r < 4; ++r)
        ob[(size_t)(o0 + r) * N_ + n] = acc[fm][fn][r] + bb[r];
    }
  }
}

// ---------------------------------------------------------------------------
extern "C" void kernel_launch(void* const* d_in, const int* in_sizes, int n_in,
                              void* d_out, int out_size, void* d_ws,
                              size_t ws_size, hipStream_t stream) {
  const float* x = (const float*)d_in[0];
  const float* source = (const float*)d_in[1];
  const float* Wq = (const float*)d_in[2];
  const float* bq = (const float*)d_in[3];
  const float* Wk = (const float*)d_in[4];
  const float* bk = (const float*)d_in[5];
  const float* Wv = (const float*)d_in[6];
  const float* bv = (const float*)d_in[7];
  const float* Wm = (const float*)d_in[8];
  const float* bm = (const float*)d_in[9];
  const float* W1 = (const float*)d_in[10];
  const float* b1 = (const float*)d_in[11];
  const float* W2 = (const float*)d_in[12];
  const float* b2 = (const float*)d_in[13];
  float* out = (float*)d_out;

  char* w = (char*)d_ws;
  size_t off = 0;
  auto alloc = [&](size_t bytes) {
    void* p = w + off;
    off = (off + bytes + 255) & ~(size_t)255;
    return p;
  };
  ushort_t* cat_t = (ushort_t*)alloc((size_t)B_ * N_ * 512 * 2);  // x^T | msg2^T
  ushort_t* st    = (ushort_t*)alloc((size_t)B_ * N_ * 256 * 2);
  ushort_t* Qt    = (ushort_t*)alloc((size_t)B_ * 4 * N_ * 64 * 2);
  ushort_t* Kt    = (ushort_t*)alloc((size_t)B_ * 4 * N_ * 64 * 2);
  ushort_t* Vt    = (ushort_t*)alloc((size_t)B_ * 256 * N_ * 2);
  ushort_t* msgT  = (ushort_t*)alloc((size_t)B_ * N_ * 256 * 2);
  ushort_t* h1t   = (ushort_t*)alloc((size_t)B_ * N_ * 512 * 2);
  ushort_t* h1n   = (ushort_t*)alloc((size_t)B_ * N_ * 512 * 2);
  float* ssum = (float*)alloc(4096 * 4);
  float* ssq  = (float*)alloc(4096 * 4);
  float* mean = (float*)alloc(4096 * 4);
  float* istd = (float*)alloc(4096 * 4);
  ushort_t* Wqb = (ushort_t*)alloc(65536 * 2);
  ushort_t* Wkb = (ushort_t*)alloc(65536 * 2);
  ushort_t* Wvb = (ushort_t*)alloc(65536 * 2);
  ushort_t* Wmb = (ushort_t*)alloc(65536 * 2);
  ushort_t* W1b = (ushort_t*)alloc(262144 * 2);
  ushort_t* W2b = (ushort_t*)alloc(131072 * 2);

  prep_weights<<<2560, 256, 0, stream>>>(Wq, Wk, Wv, Wm, W1, W2, Wqb, Wkb,
                                         Wvb, Wmb, W1b, W2b);
  transpose_in<<<dim3(32, 4, 16), 256, 0, stream>>>(x, source, cat_t, st);
  zero_stats<<<32, 256, 0, stream>>>(ssum);  // ssum+ssq contiguous (8192 f32)
  q_mfma<<<dim3(16, 2, 8), 256, 0, stream>>>(Wqb, bq, cat_t, Qt);
  kv_mfma<<<dim3(16, 2, 16), 256, 0, stream>>>(Wkb, Wvb, bk, bv, st, Kt, Vt);
  attn_mfma<<<dim3(32, 4, 8), 256, 0, stream>>>(Qt, Kt, Vt, msgT);
  merge_mfma<<<dim3(16, 2, 8), 256, 0, stream>>>(Wmb, bm, msgT, cat_t);
  w1_mfma<<<dim3(16, 4, 8), 256, 0, stream>>>(W1b, b1, cat_t, h1t);
  stats_partial<<<dim3(8, 8, 8), 256, 0, stream>>>(h1t, ssum, ssq);
  finalize_stats<<<16, 256, 0, stream>>>(ssum, ssq, mean, istd);
  normalize_h1<<<4096, 256, 0, stream>>>(h1t, mean, istd, h1n);
  w2_mfma<<<dim3(16, 2, 8), 256, 0, stream>>>(W2b, b2, h1n, out);
}